// Round 3
// baseline (97.466 us; speedup 1.0000x reference)
//
#include <hip/hip_runtime.h>
#include <stdint.h>

#define IN_F   1024
#define OUT_F  512
#define BATCH  256
#define NWORDS (IN_F / 64)   // 16 mask words of 64 bits per output node

// ---------------------------------------------------------------------------
// Kernel A: per (o,i) pair decide EDGE vs NO_EDGE and pack EDGE bits via wave
// ballot. bit = 1  <=>  EDGE (argmax index 0, i.e. !(t1 > t0); np.argmax
// tie-breaks to the first max = index 0 = edge).
// Emulates numpy's float32 op sequence exactly:
//   g = -fl32(log(fl32(-fl32(log(fl32(u+1e-10))) + 1e-10)))
//   t = fl32(e + g)
// Each f32 log computed correctly-rounded via double log (HIP logf is ~2 ulp;
// near-tied argmax decisions must match numpy's ~CR log).
// ---------------------------------------------------------------------------
__global__ __launch_bounds__(256) void mask_kernel(
    const float* __restrict__ etc,          // [OUT_F, IN_F, 2]
    const float* __restrict__ un,           // [OUT_F, IN_F, 2]
    unsigned long long* __restrict__ mask)  // [OUT_F * NWORDS], bit=1 -> edge
{
    int p = blockIdx.x * 256 + threadIdx.x;       // pair index: o*IN_F + i
    float2 e = ((const float2*)etc)[p];
    float2 u = ((const float2*)un)[p];

    float s0 = u.x + 1e-10f;
    float l0 = (float)log((double)s0);
    float m0 = -l0 + 1e-10f;
    float g0 = -(float)log((double)m0);
    float t0 = e.x + g0;

    float s1 = u.y + 1e-10f;
    float l1 = (float)log((double)s1);
    float m1 = -l1 + 1e-10f;
    float g1 = -(float)log((double)m1);
    float t1 = e.y + g1;

    // EDGE predicate: !(t1 > t0)  (strict argmax; tie -> index 0 = edge)
    unsigned long long bits = __ballot(!(t1 > t0));
    if ((threadIdx.x & 63) == 0) mask[p >> 6] = bits;
}

// ---------------------------------------------------------------------------
// Kernel B: out[b,o] = reduce over i of (edge ? x[b,i] : offset).
// Accumulator initialized to the offset reproduces the reference exactly
// (offset is the identity *and* the empty-edge-set result, since x in [0,1]).
//
// Mapping: blockIdx = b*2 + parity; thread owns o = 2*tid + parity.
//  - b uniform per block  -> float4 x loads are same-address wave broadcasts
//  - min/max branch is block-uniform (no divergence)
// ---------------------------------------------------------------------------
__global__ __launch_bounds__(256) void reduce_kernel(
    const float* __restrict__ x,                  // [BATCH, IN_F]
    const unsigned long long* __restrict__ mask,  // [OUT_F * NWORDS]
    float* __restrict__ out)                      // [BATCH, OUT_F]
{
    int b      = blockIdx.x >> 1;
    int parity = blockIdx.x & 1;
    int o      = (threadIdx.x << 1) | parity;

    const float4* x4 = (const float4*)(x + b * IN_F);
    const unsigned long long* mw = mask + o * NWORDS;

    if (parity == 0) {
        // t-norm: min, offset 2.0
        float acc = 2.0f;
        for (int w = 0; w < NWORDS; ++w) {
            unsigned long long m = mw[w];
            #pragma unroll
            for (int j = 0; j < 16; ++j) {
                float4 xv = x4[w * 16 + j];
                int k = j * 4;
                acc = fminf(acc, ((m >> k)     & 1) ? xv.x : 2.0f);
                acc = fminf(acc, ((m >> (k+1)) & 1) ? xv.y : 2.0f);
                acc = fminf(acc, ((m >> (k+2)) & 1) ? xv.z : 2.0f);
                acc = fminf(acc, ((m >> (k+3)) & 1) ? xv.w : 2.0f);
            }
        }
        out[b * OUT_F + o] = acc;
    } else {
        // t-conorm: max, offset -1.0
        float acc = -1.0f;
        for (int w = 0; w < NWORDS; ++w) {
            unsigned long long m = mw[w];
            #pragma unroll
            for (int j = 0; j < 16; ++j) {
                float4 xv = x4[w * 16 + j];
                int k = j * 4;
                acc = fmaxf(acc, ((m >> k)     & 1) ? xv.x : -1.0f);
                acc = fmaxf(acc, ((m >> (k+1)) & 1) ? xv.y : -1.0f);
                acc = fmaxf(acc, ((m >> (k+2)) & 1) ? xv.z : -1.0f);
                acc = fmaxf(acc, ((m >> (k+3)) & 1) ? xv.w : -1.0f);
            }
        }
        out[b * OUT_F + o] = acc;
    }
}

extern "C" void kernel_launch(void* const* d_in, const int* in_sizes, int n_in,
                              void* d_out, int out_size, void* d_ws, size_t ws_size,
                              hipStream_t stream) {
    const float* x   = (const float*)d_in[0];  // [BATCH, IN_F]
    const float* etc = (const float*)d_in[1];  // [OUT_F, IN_F, 2]
    const float* un  = (const float*)d_in[2];  // [OUT_F, IN_F, 2]
    float* out = (float*)d_out;                // [BATCH, OUT_F]
    unsigned long long* mask = (unsigned long long*)d_ws;  // 64 KB

    // Kernel A: 524288 pairs, one thread each
    hipLaunchKernelGGL(mask_kernel, dim3((OUT_F * IN_F) / 256), dim3(256), 0, stream,
                       etc, un, mask);
    // Kernel B: one thread per output element
    hipLaunchKernelGGL(reduce_kernel, dim3(BATCH * 2), dim3(256), 0, stream,
                       x, mask, out);
}

// Round 4
// 80.005 us; speedup vs baseline: 1.2183x; 1.2183x over previous
//
#include <hip/hip_runtime.h>
#include <stdint.h>

#define IN_F   1024
#define OUT_F  512
#define BATCH  256
#define NWORDS (IN_F / 64)   // 16 mask words of 64 bits per output node

// ---------------------------------------------------------------------------
// Kernel A: per (o,i) pair decide EDGE vs NO_EDGE, pack EDGE bits via wave
// ballot, store TRANSPOSED: mask_t[w*OUT_F + o] (w = i/64) so kernel B's
// mask loads coalesce across consecutive o.
// bit = 1  <=>  EDGE (argmax index 0, i.e. !(t1 > t0); np.argmax tie -> 0).
// Emulates numpy's float32 op sequence exactly; each f32 log computed
// correctly-rounded via double log (HIP logf ~2 ulp would risk flipping
// near-tied argmax decisions vs numpy).
// ---------------------------------------------------------------------------
__global__ __launch_bounds__(256) void mask_kernel(
    const float* __restrict__ etc,          // [OUT_F, IN_F, 2]
    const float* __restrict__ un,           // [OUT_F, IN_F, 2]
    unsigned long long* __restrict__ mask_t)// [NWORDS * OUT_F], bit=1 -> edge
{
    int p = blockIdx.x * 256 + threadIdx.x;       // pair index: o*IN_F + i
    float2 e = ((const float2*)etc)[p];
    float2 u = ((const float2*)un)[p];

    float s0 = u.x + 1e-10f;
    float l0 = (float)log((double)s0);
    float m0 = -l0 + 1e-10f;
    float g0 = -(float)log((double)m0);
    float t0 = e.x + g0;

    float s1 = u.y + 1e-10f;
    float l1 = (float)log((double)s1);
    float m1 = -l1 + 1e-10f;
    float g1 = -(float)log((double)m1);
    float t1 = e.y + g1;

    // EDGE predicate: !(t1 > t0)  (strict argmax; tie -> index 0 = edge)
    unsigned long long bits = __ballot(!(t1 > t0));
    if ((threadIdx.x & 63) == 0) {
        int o = p >> 10;              // p / IN_F
        int w = (p >> 6) & (NWORDS-1);// (i / 64)
        mask_t[w * OUT_F + o] = bits;
    }
}

// ---------------------------------------------------------------------------
// Kernel B: out[b,o] = reduce over i of (edge ? x[b,i] : offset).
// Accumulator initialized to the offset reproduces the reference exactly
// (offset is identity AND the empty-edge-set result, since x in [0,1]).
//
// blockIdx = b*2 + parity; thread owns o = 2*tid + parity.
//  - b uniform per block  -> x float4 loads are same-address wave broadcasts
//  - min/max branch block-uniform (no divergence)
//  - inner element: sbfe (0/-1 mask) + v_bfi (bit-select) + v_min/max = 3 ops
//    (bit-select of full float patterns is valid: no compares on ints)
// ---------------------------------------------------------------------------
__device__ __forceinline__ float bitsel(unsigned sel, float a, float b) {
    // sel all-ones -> a, sel zero -> b   (maps to v_bfi_b32)
    return __uint_as_float((__float_as_uint(a) & sel) | (__float_as_uint(b) & ~sel));
}
__device__ __forceinline__ unsigned sext_bit(unsigned m, int k) {
    // 0/-1 from bit k (maps to a single bfe_i32/sbfe)
    return (unsigned)((int)(m << (31 - k)) >> 31);
}

__global__ __launch_bounds__(256) void reduce_kernel(
    const float* __restrict__ x,                  // [BATCH, IN_F]
    const unsigned long long* __restrict__ mask_t,// [NWORDS * OUT_F]
    float* __restrict__ out)                      // [BATCH, OUT_F]
{
    int b      = blockIdx.x >> 1;
    int parity = blockIdx.x & 1;
    int o      = (threadIdx.x << 1) | parity;

    const float4* x4 = (const float4*)(x + b * IN_F);

    if (parity == 0) {
        // t-norm: min, offset/sentinel 2.0
        float acc = 2.0f;
        for (int w = 0; w < NWORDS; ++w) {
            unsigned long long m = mask_t[w * OUT_F + o];
            unsigned mlo = (unsigned)m, mhi = (unsigned)(m >> 32);
            #pragma unroll
            for (int j = 0; j < 8; ++j) {
                float4 xv = x4[w * 16 + j];
                int k = j * 4;
                acc = fminf(acc, bitsel(sext_bit(mlo, k),   xv.x, 2.0f));
                acc = fminf(acc, bitsel(sext_bit(mlo, k+1), xv.y, 2.0f));
                acc = fminf(acc, bitsel(sext_bit(mlo, k+2), xv.z, 2.0f));
                acc = fminf(acc, bitsel(sext_bit(mlo, k+3), xv.w, 2.0f));
            }
            #pragma unroll
            for (int j = 0; j < 8; ++j) {
                float4 xv = x4[w * 16 + 8 + j];
                int k = j * 4;
                acc = fminf(acc, bitsel(sext_bit(mhi, k),   xv.x, 2.0f));
                acc = fminf(acc, bitsel(sext_bit(mhi, k+1), xv.y, 2.0f));
                acc = fminf(acc, bitsel(sext_bit(mhi, k+2), xv.z, 2.0f));
                acc = fminf(acc, bitsel(sext_bit(mhi, k+3), xv.w, 2.0f));
            }
        }
        out[b * OUT_F + o] = acc;
    } else {
        // t-conorm: max, offset/sentinel -1.0
        float acc = -1.0f;
        for (int w = 0; w < NWORDS; ++w) {
            unsigned long long m = mask_t[w * OUT_F + o];
            unsigned mlo = (unsigned)m, mhi = (unsigned)(m >> 32);
            #pragma unroll
            for (int j = 0; j < 8; ++j) {
                float4 xv = x4[w * 16 + j];
                int k = j * 4;
                acc = fmaxf(acc, bitsel(sext_bit(mlo, k),   xv.x, -1.0f));
                acc = fmaxf(acc, bitsel(sext_bit(mlo, k+1), xv.y, -1.0f));
                acc = fmaxf(acc, bitsel(sext_bit(mlo, k+2), xv.z, -1.0f));
                acc = fmaxf(acc, bitsel(sext_bit(mlo, k+3), xv.w, -1.0f));
            }
            #pragma unroll
            for (int j = 0; j < 8; ++j) {
                float4 xv = x4[w * 16 + 8 + j];
                int k = j * 4;
                acc = fmaxf(acc, bitsel(sext_bit(mhi, k),   xv.x, -1.0f));
                acc = fmaxf(acc, bitsel(sext_bit(mhi, k+1), xv.y, -1.0f));
                acc = fmaxf(acc, bitsel(sext_bit(mhi, k+2), xv.z, -1.0f));
                acc = fmaxf(acc, bitsel(sext_bit(mhi, k+3), xv.w, -1.0f));
            }
        }
        out[b * OUT_F + o] = acc;
    }
}

extern "C" void kernel_launch(void* const* d_in, const int* in_sizes, int n_in,
                              void* d_out, int out_size, void* d_ws, size_t ws_size,
                              hipStream_t stream) {
    const float* x   = (const float*)d_in[0];  // [BATCH, IN_F]
    const float* etc = (const float*)d_in[1];  // [OUT_F, IN_F, 2]
    const float* un  = (const float*)d_in[2];  // [OUT_F, IN_F, 2]
    float* out = (float*)d_out;                // [BATCH, OUT_F]
    unsigned long long* mask_t = (unsigned long long*)d_ws;  // 64 KB

    hipLaunchKernelGGL(mask_kernel, dim3((OUT_F * IN_F) / 256), dim3(256), 0, stream,
                       etc, un, mask_t);
    hipLaunchKernelGGL(reduce_kernel, dim3(BATCH * 2), dim3(256), 0, stream,
                       x, mask_t, out);
}

// Round 5
// 78.463 us; speedup vs baseline: 1.2422x; 1.0197x over previous
//
#include <hip/hip_runtime.h>
#include <stdint.h>

#define IN_F   1024
#define OUT_F  512
#define BATCH  256

// ---------------------------------------------------------------------------
// Kernel A: per (o,i) decide EDGE (argmax idx 0) vs NO_EDGE, pack via ballot.
// Deinterleaved-by-4 layout so kernel B can use the bit-l == lane-l VCC trick
// while keeping float4 x loads:
//   mask_t[o*16 + c*4 + j], bit l  <=>  EDGE at i = c*256 + 4*l + j
// Thread mapping: block = (o, chunk c); wave j of the block covers i === j mod 4.
// Emulates numpy's f32 op sequence exactly; f32 logs computed correctly-rounded
// via double log (HIP logf ~2 ulp flips near-tied argmax decisions vs numpy).
// EDGE predicate: !(t1 > t0)  (np.argmax tie -> first max = index 0 = edge).
// ---------------------------------------------------------------------------
__global__ __launch_bounds__(256) void mask_kernel(
    const float* __restrict__ etc,          // [OUT_F, IN_F, 2]
    const float* __restrict__ un,           // [OUT_F, IN_F, 2]
    unsigned long long* __restrict__ mask_t)// [OUT_F * 16]
{
    int o = blockIdx.x >> 2;
    int c = blockIdx.x & 3;
    int j = threadIdx.x >> 6;   // wave id = sub-position within float4
    int l = threadIdx.x & 63;   // lane = bit position
    int i = c * 256 + l * 4 + j;
    int p = o * IN_F + i;

    float2 e = ((const float2*)etc)[p];
    float2 u = ((const float2*)un)[p];

    float s0 = u.x + 1e-10f;
    float l0 = (float)log((double)s0);
    float m0 = -l0 + 1e-10f;
    float g0 = -(float)log((double)m0);
    float t0 = e.x + g0;

    float s1 = u.y + 1e-10f;
    float l1 = (float)log((double)s1);
    float m1 = -l1 + 1e-10f;
    float g1 = -(float)log((double)m1);
    float t1 = e.y + g1;

    unsigned long long bits = __ballot(!(t1 > t0));   // 1 = edge
    if (l == 0) mask_t[o * 16 + c * 4 + j] = bits;
}

// ---------------------------------------------------------------------------
// Kernel B: out[b,o] = reduce_i (edge ? x[b,i] : offset), acc init = offset
// (offset is identity AND empty-edge-set result since x in [0,1]).
//
// One wave handles (b, 4 same-parity o's). Lanes span i:
//   lane l holds x[b, c*256 + 4l .. 4l+3] (coalesced float4, 1 KB/instr).
// Select: single VOP3 v_cndmask_b32 with the 64-bit mask word in an SGPR
// pair (bit l <-> lane l) -> 2 VALU ops/element (cndmask + min/max).
// Mask loads are wave-uniform (readfirstlane'd row index) -> scalar s_load.
// 4 o's/wave amortize the x-row L1 traffic 4x. Butterfly shfl_xor reduce.
// ---------------------------------------------------------------------------
__device__ __forceinline__ float csel(unsigned long long m, float xv, float sent) {
    // r = bit_lane(m) ? xv : sent   -- one v_cndmask_b32 (VOP3, sgpr-pair mask)
    float r;
    asm("v_cndmask_b32 %0, %1, %2, %3" : "=v"(r) : "v"(sent), "v"(xv), "s"(m));
    return r;
}

__global__ __launch_bounds__(256, 8) void reduce_kernel(
    const float* __restrict__ x,                   // [BATCH, IN_F]
    const unsigned long long* __restrict__ mask_t, // [OUT_F * 16]
    float* __restrict__ out)                       // [BATCH, OUT_F]
{
    int wave = threadIdx.x >> 6;
    int lane = threadIdx.x & 63;
    int W = blockIdx.x * 4 + wave;                 // 32768 wave-tasks
    int b  = __builtin_amdgcn_readfirstlane(W >> 7);
    int r  = W & 127;
    int parity = __builtin_amdgcn_readfirstlane(r & 1);
    int oq = __builtin_amdgcn_readfirstlane(r >> 1);   // 0..63: group of 4 o's

    const float4* x4 = (const float4*)(x + b * IN_F);

    // the 4 output rows this wave computes: o_g = (oq*4+g)*2 + parity
    int o0 = ((oq * 4 + 0) << 1) | parity;
    int o1 = ((oq * 4 + 1) << 1) | parity;
    int o2 = ((oq * 4 + 2) << 1) | parity;
    int o3 = ((oq * 4 + 3) << 1) | parity;
    const unsigned long long* mw0 = mask_t + o0 * 16;
    const unsigned long long* mw1 = mask_t + o1 * 16;
    const unsigned long long* mw2 = mask_t + o2 * 16;
    const unsigned long long* mw3 = mask_t + o3 * 16;

    if (parity == 0) {
        // t-norm: min, offset/sentinel 2.0
        float a0 = 2.0f, a1 = 2.0f, a2 = 2.0f, a3 = 2.0f;
        const float S = 2.0f;
        #pragma unroll
        for (int c = 0; c < 4; ++c) {
            float4 xv = x4[c * 64 + lane];
            a0 = fminf(a0, csel(mw0[c*4+0], xv.x, S));
            a0 = fminf(a0, csel(mw0[c*4+1], xv.y, S));
            a0 = fminf(a0, csel(mw0[c*4+2], xv.z, S));
            a0 = fminf(a0, csel(mw0[c*4+3], xv.w, S));
            a1 = fminf(a1, csel(mw1[c*4+0], xv.x, S));
            a1 = fminf(a1, csel(mw1[c*4+1], xv.y, S));
            a1 = fminf(a1, csel(mw1[c*4+2], xv.z, S));
            a1 = fminf(a1, csel(mw1[c*4+3], xv.w, S));
            a2 = fminf(a2, csel(mw2[c*4+0], xv.x, S));
            a2 = fminf(a2, csel(mw2[c*4+1], xv.y, S));
            a2 = fminf(a2, csel(mw2[c*4+2], xv.z, S));
            a2 = fminf(a2, csel(mw2[c*4+3], xv.w, S));
            a3 = fminf(a3, csel(mw3[c*4+0], xv.x, S));
            a3 = fminf(a3, csel(mw3[c*4+1], xv.y, S));
            a3 = fminf(a3, csel(mw3[c*4+2], xv.z, S));
            a3 = fminf(a3, csel(mw3[c*4+3], xv.w, S));
        }
        #pragma unroll
        for (int d = 32; d; d >>= 1) {
            a0 = fminf(a0, __shfl_xor(a0, d, 64));
            a1 = fminf(a1, __shfl_xor(a1, d, 64));
            a2 = fminf(a2, __shfl_xor(a2, d, 64));
            a3 = fminf(a3, __shfl_xor(a3, d, 64));
        }
        if (lane == 0) {
            float* ob = out + b * OUT_F;
            ob[o0] = a0; ob[o1] = a1; ob[o2] = a2; ob[o3] = a3;
        }
    } else {
        // t-conorm: max, offset/sentinel -1.0
        float a0 = -1.0f, a1 = -1.0f, a2 = -1.0f, a3 = -1.0f;
        const float S = -1.0f;
        #pragma unroll
        for (int c = 0; c < 4; ++c) {
            float4 xv = x4[c * 64 + lane];
            a0 = fmaxf(a0, csel(mw0[c*4+0], xv.x, S));
            a0 = fmaxf(a0, csel(mw0[c*4+1], xv.y, S));
            a0 = fmaxf(a0, csel(mw0[c*4+2], xv.z, S));
            a0 = fmaxf(a0, csel(mw0[c*4+3], xv.w, S));
            a1 = fmaxf(a1, csel(mw1[c*4+0], xv.x, S));
            a1 = fmaxf(a1, csel(mw1[c*4+1], xv.y, S));
            a1 = fmaxf(a1, csel(mw1[c*4+2], xv.z, S));
            a1 = fmaxf(a1, csel(mw1[c*4+3], xv.w, S));
            a2 = fmaxf(a2, csel(mw2[c*4+0], xv.x, S));
            a2 = fmaxf(a2, csel(mw2[c*4+1], xv.y, S));
            a2 = fmaxf(a2, csel(mw2[c*4+2], xv.z, S));
            a2 = fmaxf(a2, csel(mw2[c*4+3], xv.w, S));
            a3 = fmaxf(a3, csel(mw3[c*4+0], xv.x, S));
            a3 = fmaxf(a3, csel(mw3[c*4+1], xv.y, S));
            a3 = fmaxf(a3, csel(mw3[c*4+2], xv.z, S));
            a3 = fmaxf(a3, csel(mw3[c*4+3], xv.w, S));
        }
        #pragma unroll
        for (int d = 32; d; d >>= 1) {
            a0 = fmaxf(a0, __shfl_xor(a0, d, 64));
            a1 = fmaxf(a1, __shfl_xor(a1, d, 64));
            a2 = fmaxf(a2, __shfl_xor(a2, d, 64));
            a3 = fmaxf(a3, __shfl_xor(a3, d, 64));
        }
        if (lane == 0) {
            float* ob = out + b * OUT_F;
            ob[o0] = a0; ob[o1] = a1; ob[o2] = a2; ob[o3] = a3;
        }
    }
}

extern "C" void kernel_launch(void* const* d_in, const int* in_sizes, int n_in,
                              void* d_out, int out_size, void* d_ws, size_t ws_size,
                              hipStream_t stream) {
    const float* x   = (const float*)d_in[0];  // [BATCH, IN_F]
    const float* etc = (const float*)d_in[1];  // [OUT_F, IN_F, 2]
    const float* un  = (const float*)d_in[2];  // [OUT_F, IN_F, 2]
    float* out = (float*)d_out;                // [BATCH, OUT_F]
    unsigned long long* mask_t = (unsigned long long*)d_ws;  // 64 KB

    // Kernel A: one block per (o, 256-i chunk)
    hipLaunchKernelGGL(mask_kernel, dim3(OUT_F * 4), dim3(256), 0, stream,
                       etc, un, mask_t);
    // Kernel B: 32768 wave-tasks (b x 4 same-parity o's), 4 waves/block
    hipLaunchKernelGGL(reduce_kernel, dim3(BATCH * OUT_F / 4 / 4), dim3(256), 0, stream,
                       x, mask_t, out);
}